// Round 1
// baseline (933.381 us; speedup 1.0000x reference)
//
#include <hip/hip_runtime.h>
#include <hip/hip_bf16.h>
#include <math.h>

#define N_NODES 50000
#define N_EDGES 800000
#define DDIM    100
#define BN_EPS  1e-5f

// workspace layout (float offsets)
#define OFS_RELW   0
#define OFS_K      20480
#define OFS_Q      (OFS_K + 5000000)
#define OFS_V      (OFS_Q + 5000000)
#define OFS_FINAL  (OFS_V + 5000000)
#define OFS_ATT    (OFS_FINAL + 5000000)
#define OFS_SEGMAX (OFS_ATT + 800000)
#define OFS_DENOM  (OFS_SEGMAX + 50000)
#define OFS_SUMS   (OFS_DENOM + 50000)
#define OFS_SUMSQ  (OFS_SUMS + 128)
#define OFS_BNSC   (OFS_SUMSQ + 128)
#define OFS_BNSH   (OFS_BNSC + 128)
#define WS_FLOATS  (OFS_BNSH + 128)

// monotonic float<->uint mapping for atomicMax on floats
__device__ __forceinline__ unsigned fmap(float f) {
    unsigned u = __float_as_uint(f);
    return (u & 0x80000000u) ? ~u : (u | 0x80000000u);
}
__device__ __forceinline__ float funmap(unsigned m) {
    return (m & 0x80000000u) ? __uint_as_float(m & 0x7fffffffu) : __uint_as_float(~m);
}

// rel_w[r][c] = sum_b w_comp[r][b] * relation_att[b][c]   (200x50 @ 50x100)
__global__ __launch_bounds__(256) void relw_kernel(
    const float* __restrict__ wcomp, const float* __restrict__ ratt,
    float* __restrict__ relw)
{
    int o = blockIdx.x * 256 + threadIdx.x;
    if (o >= 200 * 100) return;
    int r = o / 100, c = o % 100;
    float acc = 0.f;
    #pragma unroll 10
    for (int b = 0; b < 50; ++b) acc += wcomp[r * 50 + b] * ratt[b * 100 + c];
    relw[o] = acc;
}

// fused projections: k,q,v -> ws ; s -> d_out
__global__ __launch_bounds__(320) void proj_kernel(
    const float* __restrict__ X,
    const float* __restrict__ Wk, const float* __restrict__ bk,
    const float* __restrict__ Wq, const float* __restrict__ bq,
    const float* __restrict__ Wv, const float* __restrict__ bv,
    const float* __restrict__ Ws, const float* __restrict__ bs,
    float* __restrict__ ko, float* __restrict__ qo,
    float* __restrict__ vo, float* __restrict__ so)
{
    __shared__ float Xs[64][101];
    __shared__ float Wl[100][101];
    const int tid = threadIdx.x;
    const int nb = blockIdx.x * 64;

    for (int idx = tid; idx < 64 * 100; idx += 320) {
        int n = idx / 100, d = idx % 100;
        int node = nb + n;
        Xs[n][d] = (node < N_NODES) ? X[node * 100 + d] : 0.f;
    }

    const float* Wm[4] = {Wk, Wq, Wv, Ws};
    const float* bm[4] = {bk, bq, bv, bs};
    float*       om[4] = {ko, qo, vo, so};

    const int tc = tid % 20;   // col group: c = tc + 20*i
    const int tn = tid / 20;   // node group: n = tn + 16*j

    for (int m = 0; m < 4; ++m) {
        __syncthreads();
        const float* W = Wm[m];
        for (int idx = tid; idx < 100 * 100; idx += 320)
            Wl[idx / 100][idx % 100] = W[idx];
        __syncthreads();

        float acc[4][5];
        #pragma unroll
        for (int j = 0; j < 4; ++j)
            #pragma unroll
            for (int i = 0; i < 5; ++i) acc[j][i] = 0.f;

        #pragma unroll 4
        for (int d = 0; d < 100; ++d) {
            float xr[4], wr[5];
            #pragma unroll
            for (int j = 0; j < 4; ++j) xr[j] = Xs[tn + 16 * j][d];
            #pragma unroll
            for (int i = 0; i < 5; ++i) wr[i] = Wl[tc + 20 * i][d];
            #pragma unroll
            for (int j = 0; j < 4; ++j)
                #pragma unroll
                for (int i = 0; i < 5; ++i) acc[j][i] += xr[j] * wr[i];
        }

        const float* bias = bm[m];
        float* out = om[m];
        #pragma unroll
        for (int j = 0; j < 4; ++j) {
            int node = nb + tn + 16 * j;
            if (node < N_NODES) {
                #pragma unroll
                for (int i = 0; i < 5; ++i) {
                    int c = tc + 20 * i;
                    out[node * 100 + c] = acc[j][i] + bias[c];
                }
            }
        }
    }
}

// per-edge attention logit + segment max (16 lanes per edge)
__global__ __launch_bounds__(256) void att_kernel(
    const float* __restrict__ k, const float* __restrict__ q,
    const float* __restrict__ relw,
    const int* __restrict__ src, const int* __restrict__ dst,
    const int* __restrict__ etype,
    float* __restrict__ att, unsigned* __restrict__ segmax)
{
    const int lane = threadIdx.x & 15;
    const int e = blockIdx.x * 16 + (threadIdx.x >> 4);
    if (e >= N_EDGES) return;
    const int s_ = src[e], d_ = dst[e], t_ = etype[e];
    const float* kk = k + s_ * 100;
    const float* qq = q + d_ * 100;
    const float* ww = relw + t_ * 100;
    float acc = 0.f;
    #pragma unroll
    for (int i = 0; i < 7; ++i) {
        int d = lane + 16 * i;
        if (d < 100) acc += kk[d] * ww[d] * qq[d];
    }
    #pragma unroll
    for (int off = 8; off > 0; off >>= 1) acc += __shfl_xor(acc, off, 16);
    if (lane == 0) {
        att[e] = acc;
        atomicMax(&segmax[d_], fmap(acc));
    }
}

// e = exp(att - segmax[dst]); denom[dst] += e
__global__ __launch_bounds__(256) void exp_kernel(
    float* __restrict__ att, const int* __restrict__ dst,
    const unsigned* __restrict__ segmax, float* __restrict__ denom)
{
    int e = blockIdx.x * 256 + threadIdx.x;
    if (e >= N_EDGES) return;
    int d_ = dst[e];
    float mx = funmap(segmax[d_]);
    float w = __expf(att[e] - mx);
    att[e] = w;
    atomicAdd(&denom[d_], w);
}

// final[dst] += (att/denom[dst]) * v[src]   (16 lanes per edge)
__global__ __launch_bounds__(256) void final_kernel(
    const float* __restrict__ att, const float* __restrict__ v,
    const int* __restrict__ src, const int* __restrict__ dst,
    const float* __restrict__ denom, float* __restrict__ fin)
{
    const int lane = threadIdx.x & 15;
    const int e = blockIdx.x * 16 + (threadIdx.x >> 4);
    if (e >= N_EDGES) return;
    const int s_ = src[e], d_ = dst[e];
    const float w = att[e] / denom[d_];
    const float* vv = v + s_ * 100;
    float* ff = fin + d_ * 100;
    #pragma unroll
    for (int i = 0; i < 7; ++i) {
        int d = lane + 16 * i;
        if (d < 100) atomicAdd(&ff[d], w * vv[d]);
    }
}

// n_pre = a*s + (1-a)*final (in place into d_out) + per-column sum/sumsq
__global__ __launch_bounds__(256) void combine_kernel(
    const float* __restrict__ fin, const float* __restrict__ alpha,
    float* __restrict__ out, float* __restrict__ sums, float* __restrict__ sumsq)
{
    __shared__ float ls[100], lq[100];
    const int tid = threadIdx.x;
    if (tid < 100) { ls[tid] = 0.f; lq[tid] = 0.f; }
    __syncthreads();
    const float a = 1.f / (1.f + __expf(-alpha[0]));
    const float b = 1.f - a;
    for (int idx = blockIdx.x * 256 + tid; idx < N_NODES * 100; idx += gridDim.x * 256) {
        int c = idx % 100;
        float val = a * out[idx] + b * fin[idx];
        out[idx] = val;
        atomicAdd(&ls[c], val);
        atomicAdd(&lq[c], val * val);
    }
    __syncthreads();
    if (tid < 100) {
        atomicAdd(&sums[tid], ls[tid]);
        atomicAdd(&sumsq[tid], lq[tid]);
    }
}

__global__ __launch_bounds__(128) void bnfin_kernel(
    const float* __restrict__ sums, const float* __restrict__ sumsq,
    const float* __restrict__ gamma, const float* __restrict__ beta,
    float* __restrict__ bnsc, float* __restrict__ bnsh)
{
    int c = threadIdx.x;
    if (c >= 100) return;
    float inv_n = 1.f / (float)N_NODES;
    float mean = sums[c] * inv_n;
    float var = sumsq[c] * inv_n - mean * mean;
    float sc = gamma[c] * rsqrtf(var + BN_EPS);
    bnsc[c] = sc;
    bnsh[c] = beta[c] - mean * sc;
}

__global__ __launch_bounds__(256) void apply_kernel(
    float* __restrict__ out, const float* __restrict__ bnsc,
    const float* __restrict__ bnsh)
{
    for (int idx = blockIdx.x * 256 + threadIdx.x; idx < N_NODES * 100; idx += gridDim.x * 256) {
        int c = idx % 100;
        out[idx] = tanhf(out[idx] * bnsc[c] + bnsh[c]);
    }
}

// r_out[r][c] = r_feats[r] . Wr[c] + br[c]   (loop_rel row is dropped by ref)
__global__ __launch_bounds__(256) void rout_kernel(
    const float* __restrict__ rf, const float* __restrict__ Wr,
    const float* __restrict__ br, float* __restrict__ out)
{
    int o = blockIdx.x * 256 + threadIdx.x;
    if (o >= 200 * 100) return;
    int r = o / 100, c = o % 100;
    float acc = br[c];
    #pragma unroll 10
    for (int d = 0; d < 100; ++d) acc += rf[r * 100 + d] * Wr[c * 100 + d];
    out[N_NODES * 100 + o] = acc;
}

extern "C" void kernel_launch(void* const* d_in, const int* in_sizes, int n_in,
                              void* d_out, int out_size, void* d_ws, size_t ws_size,
                              hipStream_t stream) {
    const float* X     = (const float*)d_in[0];
    const float* rfeat = (const float*)d_in[1];
    const int*   src   = (const int*)d_in[2];
    const int*   dst   = (const int*)d_in[3];
    const int*   ety   = (const int*)d_in[4];
    const float* Wsw   = (const float*)d_in[6];
    const float* Wsb   = (const float*)d_in[7];
    const float* Wkw   = (const float*)d_in[8];
    const float* Wkb   = (const float*)d_in[9];
    const float* Wqw   = (const float*)d_in[10];
    const float* Wqb   = (const float*)d_in[11];
    const float* Wvw   = (const float*)d_in[12];
    const float* Wvb   = (const float*)d_in[13];
    const float* Wrw   = (const float*)d_in[14];
    const float* Wrb   = (const float*)d_in[15];
    const float* ratt  = (const float*)d_in[16];
    const float* wcomp = (const float*)d_in[17];
    const float* alpha = (const float*)d_in[18];
    const float* gamma = (const float*)d_in[20];
    const float* beta  = (const float*)d_in[21];

    float* out = (float*)d_out;
    float* ws  = (float*)d_ws;
    if (ws_size < (size_t)WS_FLOATS * sizeof(float)) return;

    float*    relw   = ws + OFS_RELW;
    float*    k      = ws + OFS_K;
    float*    q      = ws + OFS_Q;
    float*    v      = ws + OFS_V;
    float*    fin    = ws + OFS_FINAL;
    float*    att    = ws + OFS_ATT;
    unsigned* segmax = (unsigned*)(ws + OFS_SEGMAX);
    float*    denom  = ws + OFS_DENOM;
    float*    sums   = ws + OFS_SUMS;
    float*    sumsq  = ws + OFS_SUMSQ;
    float*    bnsc   = ws + OFS_BNSC;
    float*    bnsh   = ws + OFS_BNSH;

    // zero-init accumulators (segmax=0 maps to -inf-ish under fmap ordering)
    hipMemsetAsync(fin, 0, (size_t)N_NODES * 100 * sizeof(float), stream);
    hipMemsetAsync(segmax, 0, (size_t)(50000 + 50000) * sizeof(float), stream);
    hipMemsetAsync(sums, 0, 256 * sizeof(float), stream);

    relw_kernel<<<(20000 + 255) / 256, 256, 0, stream>>>(wcomp, ratt, relw);
    proj_kernel<<<(N_NODES + 63) / 64, 320, 0, stream>>>(
        X, Wkw, Wkb, Wqw, Wqb, Wvw, Wvb, Wsw, Wsb, k, q, v, out);
    att_kernel<<<(N_EDGES + 15) / 16, 256, 0, stream>>>(k, q, relw, src, dst, ety, att, segmax);
    exp_kernel<<<(N_EDGES + 255) / 256, 256, 0, stream>>>(att, dst, segmax, denom);
    final_kernel<<<(N_EDGES + 15) / 16, 256, 0, stream>>>(att, v, src, dst, denom, fin);
    combine_kernel<<<2048, 256, 0, stream>>>(fin, alpha, out, sums, sumsq);
    bnfin_kernel<<<1, 128, 0, stream>>>(sums, sumsq, gamma, beta, bnsc, bnsh);
    apply_kernel<<<2048, 256, 0, stream>>>(out, bnsc, bnsh);
    rout_kernel<<<(20000 + 255) / 256, 256, 0, stream>>>(rfeat, Wrw, Wrb, out);
}

// Round 2
// 824.171 us; speedup vs baseline: 1.1325x; 1.1325x over previous
//
#include <hip/hip_runtime.h>
#include <hip/hip_bf16.h>
#include <math.h>

#define N_NODES 50000
#define N_EDGES 800000
#define BN_EPS  1e-5f
#define SCAN_NB 49   // ceil(50000/1024)

// ---- workspace layout (float-element offsets) ----
#define OFS_RELW   0
#define OFS_K      20480
#define OFS_Q      (OFS_K + 5000000)
#define OFS_V      (OFS_Q + 5000000)
#define OFS_ATTP   (OFS_V + 5000000)
#define OFS_SUMS   (OFS_ATTP + 800000)
#define OFS_SUMSQ  (OFS_SUMS + 128)
#define OFS_BNSC   (OFS_SUMSQ + 128)
#define OFS_BNSH   (OFS_BNSC + 128)
// int region starts here
#define OFS_CNT    (OFS_BNSH + 128)
#define OFS_PART   (OFS_CNT + 50176)
#define OFS_BSUM   (OFS_PART + 50176)
#define OFS_OFFS   (OFS_BSUM + 64)
#define OFS_CURS   (OFS_OFFS + 50176)
#define OFS_PERM   (OFS_CURS + 50176)
#define WS_ELEMS   (OFS_PERM + 800000)

// rel_w[r][c] = sum_b w_comp[r][b] * relation_att[b][c]   (200x50 @ 50x100)
__global__ __launch_bounds__(256) void relw_kernel(
    const float* __restrict__ wcomp, const float* __restrict__ ratt,
    float* __restrict__ relw)
{
    int o = blockIdx.x * 256 + threadIdx.x;
    if (o >= 200 * 100) return;
    int r = o / 100, c = o % 100;
    float acc = 0.f;
    #pragma unroll 10
    for (int b = 0; b < 50; ++b) acc += wcomp[r * 50 + b] * ratt[b * 100 + c];
    relw[o] = acc;
}

// fused projections: k,q,v -> ws ; s -> d_out
__global__ __launch_bounds__(320) void proj_kernel(
    const float* __restrict__ X,
    const float* __restrict__ Wk, const float* __restrict__ bk,
    const float* __restrict__ Wq, const float* __restrict__ bq,
    const float* __restrict__ Wv, const float* __restrict__ bv,
    const float* __restrict__ Ws, const float* __restrict__ bs,
    float* __restrict__ ko, float* __restrict__ qo,
    float* __restrict__ vo, float* __restrict__ so)
{
    __shared__ float Xs[64][101];
    __shared__ float Wl[100][101];
    const int tid = threadIdx.x;
    const int nb = blockIdx.x * 64;

    for (int idx = tid; idx < 64 * 100; idx += 320) {
        int n = idx / 100, d = idx % 100;
        int node = nb + n;
        Xs[n][d] = (node < N_NODES) ? X[node * 100 + d] : 0.f;
    }

    const float* Wm[4] = {Wk, Wq, Wv, Ws};
    const float* bm[4] = {bk, bq, bv, bs};
    float*       om[4] = {ko, qo, vo, so};

    const int tc = tid % 20;
    const int tn = tid / 20;

    for (int m = 0; m < 4; ++m) {
        __syncthreads();
        const float* W = Wm[m];
        for (int idx = tid; idx < 100 * 100; idx += 320)
            Wl[idx / 100][idx % 100] = W[idx];
        __syncthreads();

        float acc[4][5];
        #pragma unroll
        for (int j = 0; j < 4; ++j)
            #pragma unroll
            for (int i = 0; i < 5; ++i) acc[j][i] = 0.f;

        #pragma unroll 4
        for (int d = 0; d < 100; ++d) {
            float xr[4], wr[5];
            #pragma unroll
            for (int j = 0; j < 4; ++j) xr[j] = Xs[tn + 16 * j][d];
            #pragma unroll
            for (int i = 0; i < 5; ++i) wr[i] = Wl[tc + 20 * i][d];
            #pragma unroll
            for (int j = 0; j < 4; ++j)
                #pragma unroll
                for (int i = 0; i < 5; ++i) acc[j][i] += xr[j] * wr[i];
        }

        const float* bias = bm[m];
        float* outp = om[m];
        #pragma unroll
        for (int j = 0; j < 4; ++j) {
            int node = nb + tn + 16 * j;
            if (node < N_NODES) {
                #pragma unroll
                for (int i = 0; i < 5; ++i) {
                    int c = tc + 20 * i;
                    outp[node * 100 + c] = acc[j][i] + bias[c];
                }
            }
        }
    }
}

// histogram of dst
__global__ __launch_bounds__(256) void hist_kernel(
    const int* __restrict__ dst, int* __restrict__ cnt)
{
    int e = blockIdx.x * 256 + threadIdx.x;
    if (e < N_EDGES) atomicAdd(&cnt[dst[e]], 1);
}

// block-level exclusive scan (1024/block)
__global__ __launch_bounds__(1024) void scanA_kernel(
    const int* __restrict__ cnt, int* __restrict__ partial, int* __restrict__ bsum)
{
    __shared__ int buf[1024];
    int tid = threadIdx.x;
    int i = blockIdx.x * 1024 + tid;
    int val = (i < N_NODES) ? cnt[i] : 0;
    buf[tid] = val;
    __syncthreads();
    for (int off = 1; off < 1024; off <<= 1) {
        int t = (tid >= off) ? buf[tid - off] : 0;
        __syncthreads();
        buf[tid] += t;
        __syncthreads();
    }
    int incl = buf[tid];
    if (i < N_NODES) partial[i] = incl - val;
    if (tid == 1023) bsum[blockIdx.x] = incl;
}

// scan block sums + produce final offsets
__global__ __launch_bounds__(1024) void scanB_kernel(
    const int* __restrict__ partial, const int* __restrict__ bsum,
    int* __restrict__ offs)
{
    __shared__ int bs[64];
    int tid = threadIdx.x;
    if (tid < SCAN_NB) bs[tid] = bsum[tid];
    __syncthreads();
    if (tid == 0) {
        int run = 0;
        for (int b = 0; b < SCAN_NB; ++b) { int t = bs[b]; bs[b] = run; run += t; }
    }
    __syncthreads();
    for (int i = tid; i < N_NODES; i += 1024) offs[i] = partial[i] + bs[i >> 10];
    if (tid == 0) offs[N_NODES] = N_EDGES;
}

// scatter edge ids into dst-sorted order
__global__ __launch_bounds__(256) void scatter_kernel(
    const int* __restrict__ dst, const int* __restrict__ offs,
    int* __restrict__ cursor, int* __restrict__ perm)
{
    int e = blockIdx.x * 256 + threadIdx.x;
    if (e >= N_EDGES) return;
    int d = dst[e];
    int p = atomicAdd(&cursor[d], 1);
    perm[offs[d] + p] = e;
}

// attention logits in CSR position order (16 lanes per position)
__global__ __launch_bounds__(256) void attp_kernel(
    const float* __restrict__ k, const float* __restrict__ q,
    const float* __restrict__ relw, const int* __restrict__ perm,
    const int* __restrict__ src, const int* __restrict__ dst,
    const int* __restrict__ etype, float* __restrict__ attp)
{
    const int lane = threadIdx.x & 15;
    const int i = blockIdx.x * 16 + (threadIdx.x >> 4);
    if (i >= N_EDGES) return;
    const int e = perm[i];
    const int s_ = src[e], d_ = dst[e], t_ = etype[e];
    const float* kk = k + (size_t)s_ * 100;
    const float* qq = q + (size_t)d_ * 100;
    const float* ww = relw + t_ * 100;
    float acc = 0.f;
    #pragma unroll
    for (int it = 0; it < 7; ++it) {
        int d = lane + 16 * it;
        if (d < 100) acc += kk[d] * ww[d] * qq[d];
    }
    #pragma unroll
    for (int off = 8; off > 0; off >>= 1) acc += __shfl_xor(acc, off, 16);
    if (lane == 0) attp[i] = acc;
}

// one wave per node: segment softmax + weighted-V aggregate + gated combine
// + BN column partial sums (lane-fixed columns -> register accumulators)
__global__ __launch_bounds__(256) void agg_kernel(
    const int* __restrict__ offs, const int* __restrict__ perm,
    const int* __restrict__ src, const float* __restrict__ attp,
    const float* __restrict__ v, const float* __restrict__ alpha,
    float* __restrict__ out, float* __restrict__ gsums, float* __restrict__ gsumsq)
{
    __shared__ float ls[100], lq[100];
    const int tid = threadIdx.x;
    if (tid < 100) { ls[tid] = 0.f; lq[tid] = 0.f; }
    __syncthreads();
    const int lane = tid & 63;
    const int gwave = blockIdx.x * 4 + (tid >> 6);
    const int nwaves = gridDim.x * 4;
    const float a = 1.f / (1.f + __expf(-alpha[0]));
    const float b = 1.f - a;
    const int c0 = lane, c1 = lane + 64;
    const bool has1 = (c1 < 100);
    float s0 = 0.f, s1 = 0.f, q0 = 0.f, q1 = 0.f;

    for (int n = gwave; n < N_NODES; n += nwaves) {
        const int beg = offs[n], end = offs[n + 1];
        // pass 1: segment max
        float m = -INFINITY;
        for (int i = beg + lane; i < end; i += 64) m = fmaxf(m, attp[i]);
        #pragma unroll
        for (int off = 32; off > 0; off >>= 1) m = fmaxf(m, __shfl_xor(m, off, 64));
        // pass 2: denom
        float dsum = 0.f;
        for (int i = beg + lane; i < end; i += 64) dsum += __expf(attp[i] - m);
        #pragma unroll
        for (int off = 32; off > 0; off >>= 1) dsum += __shfl_xor(dsum, off, 64);
        const float inv = (end > beg) ? 1.f / dsum : 0.f;
        // pass 3: weighted aggregate (columns lane-parallel, edges serial)
        float a0 = 0.f, a1 = 0.f;
        for (int i = beg; i < end; ++i) {
            const int e = perm[i];                 // uniform across wave
            const float w = __expf(attp[i] - m) * inv;
            const float* vv = v + (size_t)src[e] * 100;
            a0 += w * vv[c0];
            if (has1) a1 += w * vv[c1];
        }
        // gated combine in place, track BN stats
        float* po = out + (size_t)n * 100;
        float val0 = a * po[c0] + b * a0;
        po[c0] = val0;
        s0 += val0; q0 += val0 * val0;
        if (has1) {
            float val1 = a * po[c1] + b * a1;
            po[c1] = val1;
            s1 += val1; q1 += val1 * val1;
        }
    }
    atomicAdd(&ls[c0], s0); atomicAdd(&lq[c0], q0);
    if (has1) { atomicAdd(&ls[c1], s1); atomicAdd(&lq[c1], q1); }
    __syncthreads();
    if (tid < 100) {
        atomicAdd(&gsums[tid], ls[tid]);
        atomicAdd(&gsumsq[tid], lq[tid]);
    }
}

__global__ __launch_bounds__(128) void bnfin_kernel(
    const float* __restrict__ sums, const float* __restrict__ sumsq,
    const float* __restrict__ gamma, const float* __restrict__ beta,
    float* __restrict__ bnsc, float* __restrict__ bnsh)
{
    int c = threadIdx.x;
    if (c >= 100) return;
    float inv_n = 1.f / (float)N_NODES;
    float mean = sums[c] * inv_n;
    float var = sumsq[c] * inv_n - mean * mean;
    float sc = gamma[c] * rsqrtf(var + BN_EPS);
    bnsc[c] = sc;
    bnsh[c] = beta[c] - mean * sc;
}

__global__ __launch_bounds__(256) void apply_kernel(
    float* __restrict__ out, const float* __restrict__ bnsc,
    const float* __restrict__ bnsh)
{
    for (int idx = blockIdx.x * 256 + threadIdx.x; idx < N_NODES * 100; idx += gridDim.x * 256) {
        int c = idx % 100;
        out[idx] = tanhf(out[idx] * bnsc[c] + bnsh[c]);
    }
}

// r_out[r][c] = r_feats[r] . Wr[c] + br[c]   (loop_rel row dropped by ref)
__global__ __launch_bounds__(256) void rout_kernel(
    const float* __restrict__ rf, const float* __restrict__ Wr,
    const float* __restrict__ br, float* __restrict__ out)
{
    int o = blockIdx.x * 256 + threadIdx.x;
    if (o >= 200 * 100) return;
    int r = o / 100, c = o % 100;
    float acc = br[c];
    #pragma unroll 10
    for (int d = 0; d < 100; ++d) acc += rf[r * 100 + d] * Wr[c * 100 + d];
    out[N_NODES * 100 + o] = acc;
}

extern "C" void kernel_launch(void* const* d_in, const int* in_sizes, int n_in,
                              void* d_out, int out_size, void* d_ws, size_t ws_size,
                              hipStream_t stream) {
    const float* X     = (const float*)d_in[0];
    const float* rfeat = (const float*)d_in[1];
    const int*   src   = (const int*)d_in[2];
    const int*   dst   = (const int*)d_in[3];
    const int*   ety   = (const int*)d_in[4];
    const float* Wsw   = (const float*)d_in[6];
    const float* Wsb   = (const float*)d_in[7];
    const float* Wkw   = (const float*)d_in[8];
    const float* Wkb   = (const float*)d_in[9];
    const float* Wqw   = (const float*)d_in[10];
    const float* Wqb   = (const float*)d_in[11];
    const float* Wvw   = (const float*)d_in[12];
    const float* Wvb   = (const float*)d_in[13];
    const float* Wrw   = (const float*)d_in[14];
    const float* Wrb   = (const float*)d_in[15];
    const float* ratt  = (const float*)d_in[16];
    const float* wcomp = (const float*)d_in[17];
    const float* alpha = (const float*)d_in[18];
    const float* gamma = (const float*)d_in[20];
    const float* beta  = (const float*)d_in[21];

    float* out = (float*)d_out;
    float* ws  = (float*)d_ws;
    if (ws_size < (size_t)WS_ELEMS * sizeof(float)) return;

    float* relw  = ws + OFS_RELW;
    float* k     = ws + OFS_K;
    float* q     = ws + OFS_Q;
    float* v     = ws + OFS_V;
    float* attp  = ws + OFS_ATTP;
    float* sums  = ws + OFS_SUMS;
    float* sumsq = ws + OFS_SUMSQ;
    float* bnsc  = ws + OFS_BNSC;
    float* bnsh  = ws + OFS_BNSH;
    int* cnt     = (int*)(ws + OFS_CNT);
    int* partial = (int*)(ws + OFS_PART);
    int* bsum    = (int*)(ws + OFS_BSUM);
    int* offs    = (int*)(ws + OFS_OFFS);
    int* cursor  = (int*)(ws + OFS_CURS);
    int* perm    = (int*)(ws + OFS_PERM);

    hipMemsetAsync(cnt, 0, 50000 * sizeof(int), stream);
    hipMemsetAsync(cursor, 0, 50000 * sizeof(int), stream);
    hipMemsetAsync(sums, 0, 256 * sizeof(float), stream);

    relw_kernel<<<(20000 + 255) / 256, 256, 0, stream>>>(wcomp, ratt, relw);
    proj_kernel<<<(N_NODES + 63) / 64, 320, 0, stream>>>(
        X, Wkw, Wkb, Wqw, Wqb, Wvw, Wvb, Wsw, Wsb, k, q, v, out);

    hist_kernel<<<(N_EDGES + 255) / 256, 256, 0, stream>>>(dst, cnt);
    scanA_kernel<<<SCAN_NB, 1024, 0, stream>>>(cnt, partial, bsum);
    scanB_kernel<<<1, 1024, 0, stream>>>(partial, bsum, offs);
    scatter_kernel<<<(N_EDGES + 255) / 256, 256, 0, stream>>>(dst, offs, cursor, perm);

    attp_kernel<<<(N_EDGES + 15) / 16, 256, 0, stream>>>(
        k, q, relw, perm, src, dst, ety, attp);
    agg_kernel<<<512, 256, 0, stream>>>(offs, perm, src, attp, v, alpha, out, sums, sumsq);
    bnfin_kernel<<<1, 128, 0, stream>>>(sums, sumsq, gamma, beta, bnsc, bnsh);
    apply_kernel<<<2048, 256, 0, stream>>>(out, bnsc, bnsh);
    rout_kernel<<<(20000 + 255) / 256, 256, 0, stream>>>(rfeat, Wrw, Wrb, out);
}

// Round 3
// 540.162 us; speedup vs baseline: 1.7280x; 1.5258x over previous
//
#include <hip/hip_runtime.h>
#include <hip/hip_bf16.h>
#include <math.h>

#define N_NODES 50000
#define N_EDGES 800000
#define BN_EPS  1e-5f
#define SCAN_NB 49     // ceil(50000/1024)
#define AGG_NB  2048   // agg grid blocks

// ---- workspace layout (float-element offsets) ----
#define OFS_RELW   0
#define OFS_K      20480
#define OFS_Q      (OFS_K + 5000000)
#define OFS_V      (OFS_Q + 5000000)
#define OFS_ATTP   (OFS_V + 5000000)
#define OFS_BNPART (OFS_ATTP + 800000)          // 200 * AGG_NB
#define OFS_BNSC   (OFS_BNPART + 200 * AGG_NB)
#define OFS_BNSH   (OFS_BNSC + 128)
// int region
#define OFS_CNT    (OFS_BNSH + 128)
#define OFS_PART   (OFS_CNT + 50176)
#define OFS_BSUM   (OFS_PART + 50176)
#define OFS_OFFS   (OFS_BSUM + 64)
#define OFS_CURS   (OFS_OFFS + 50176)
#define OFS_PERM   (OFS_CURS + 50176)
#define OFS_PSRC   (OFS_PERM + 800000)
#define WS_ELEMS   (OFS_PSRC + 800000)

// rel_w[r][c] = sum_b w_comp[r][b] * relation_att[b][c]
__global__ __launch_bounds__(256) void relw_kernel(
    const float* __restrict__ wcomp, const float* __restrict__ ratt,
    float* __restrict__ relw)
{
    int o = blockIdx.x * 256 + threadIdx.x;
    if (o >= 200 * 100) return;
    int r = o / 100, c = o % 100;
    float acc = 0.f;
    #pragma unroll 10
    for (int b = 0; b < 50; ++b) acc += wcomp[r * 50 + b] * ratt[b * 100 + c];
    relw[o] = acc;
}

// fused projections: k,q,v -> ws ; s -> d_out
__global__ __launch_bounds__(320) void proj_kernel(
    const float* __restrict__ X,
    const float* __restrict__ Wk, const float* __restrict__ bk,
    const float* __restrict__ Wq, const float* __restrict__ bq,
    const float* __restrict__ Wv, const float* __restrict__ bv,
    const float* __restrict__ Ws, const float* __restrict__ bs,
    float* __restrict__ ko, float* __restrict__ qo,
    float* __restrict__ vo, float* __restrict__ so)
{
    __shared__ float Xs[64][101];
    __shared__ float Wl[100][101];
    const int tid = threadIdx.x;
    const int nb = blockIdx.x * 64;

    for (int idx = tid; idx < 64 * 100; idx += 320) {
        int n = idx / 100, d = idx % 100;
        int node = nb + n;
        Xs[n][d] = (node < N_NODES) ? X[node * 100 + d] : 0.f;
    }

    const float* Wm[4] = {Wk, Wq, Wv, Ws};
    const float* bm[4] = {bk, bq, bv, bs};
    float*       om[4] = {ko, qo, vo, so};

    const int tc = tid % 20;
    const int tn = tid / 20;

    for (int m = 0; m < 4; ++m) {
        __syncthreads();
        const float* W = Wm[m];
        for (int idx = tid; idx < 100 * 100; idx += 320)
            Wl[idx / 100][idx % 100] = W[idx];
        __syncthreads();

        float acc[4][5];
        #pragma unroll
        for (int j = 0; j < 4; ++j)
            #pragma unroll
            for (int i = 0; i < 5; ++i) acc[j][i] = 0.f;

        #pragma unroll 4
        for (int d = 0; d < 100; ++d) {
            float xr[4], wr[5];
            #pragma unroll
            for (int j = 0; j < 4; ++j) xr[j] = Xs[tn + 16 * j][d];
            #pragma unroll
            for (int i = 0; i < 5; ++i) wr[i] = Wl[tc + 20 * i][d];
            #pragma unroll
            for (int j = 0; j < 4; ++j)
                #pragma unroll
                for (int i = 0; i < 5; ++i) acc[j][i] += xr[j] * wr[i];
        }

        const float* bias = bm[m];
        float* outp = om[m];
        #pragma unroll
        for (int j = 0; j < 4; ++j) {
            int node = nb + tn + 16 * j;
            if (node < N_NODES) {
                #pragma unroll
                for (int i = 0; i < 5; ++i) {
                    int c = tc + 20 * i;
                    outp[node * 100 + c] = acc[j][i] + bias[c];
                }
            }
        }
    }
}

__global__ __launch_bounds__(256) void hist_kernel(
    const int* __restrict__ dst, int* __restrict__ cnt)
{
    int e = blockIdx.x * 256 + threadIdx.x;
    if (e < N_EDGES) atomicAdd(&cnt[dst[e]], 1);
}

__global__ __launch_bounds__(1024) void scanA_kernel(
    const int* __restrict__ cnt, int* __restrict__ partial, int* __restrict__ bsum)
{
    __shared__ int buf[1024];
    int tid = threadIdx.x;
    int i = blockIdx.x * 1024 + tid;
    int val = (i < N_NODES) ? cnt[i] : 0;
    buf[tid] = val;
    __syncthreads();
    for (int off = 1; off < 1024; off <<= 1) {
        int t = (tid >= off) ? buf[tid - off] : 0;
        __syncthreads();
        buf[tid] += t;
        __syncthreads();
    }
    int incl = buf[tid];
    if (i < N_NODES) partial[i] = incl - val;
    if (tid == 1023) bsum[blockIdx.x] = incl;
}

__global__ __launch_bounds__(1024) void scanB_kernel(
    const int* __restrict__ partial, const int* __restrict__ bsum,
    int* __restrict__ offs)
{
    __shared__ int bs[64];
    int tid = threadIdx.x;
    if (tid < SCAN_NB) bs[tid] = bsum[tid];
    __syncthreads();
    if (tid == 0) {
        int run = 0;
        for (int b = 0; b < SCAN_NB; ++b) { int t = bs[b]; bs[b] = run; run += t; }
    }
    __syncthreads();
    for (int i = tid; i < N_NODES; i += 1024) offs[i] = partial[i] + bs[i >> 10];
    if (tid == 0) offs[N_NODES] = N_EDGES;
}

// scatter edge ids + their src into dst-sorted order
__global__ __launch_bounds__(256) void scatter_kernel(
    const int* __restrict__ src, const int* __restrict__ dst,
    const int* __restrict__ offs, int* __restrict__ cursor,
    int* __restrict__ perm, int* __restrict__ psrc)
{
    int e = blockIdx.x * 256 + threadIdx.x;
    if (e >= N_EDGES) return;
    int d = dst[e];
    int p = atomicAdd(&cursor[d], 1);
    int pos = offs[d] + p;
    perm[pos] = e;
    psrc[pos] = src[e];
}

// attention logits in CSR position order: 32 lanes/edge, float4 row loads
__global__ __launch_bounds__(256) void attp_kernel(
    const float* __restrict__ k, const float* __restrict__ q,
    const float* __restrict__ relw, const int* __restrict__ perm,
    const int* __restrict__ src, const int* __restrict__ dst,
    const int* __restrict__ etype, float* __restrict__ attp)
{
    const int lane = threadIdx.x & 31;
    const int i = blockIdx.x * 8 + (threadIdx.x >> 5);
    if (i >= N_EDGES) return;
    const int e = perm[i];
    const int s_ = src[e], d_ = dst[e], t_ = etype[e];
    float acc = 0.f;
    if (lane < 25) {
        const float4 kv = ((const float4*)(k + (size_t)s_ * 100))[lane];
        const float4 qv = ((const float4*)(q + (size_t)d_ * 100))[lane];
        const float4 wv = ((const float4*)(relw + t_ * 100))[lane];
        acc = kv.x * wv.x * qv.x + kv.y * wv.y * qv.y
            + kv.z * wv.z * qv.z + kv.w * wv.w * qv.w;
    }
    #pragma unroll
    for (int off = 16; off > 0; off >>= 1) acc += __shfl_xor(acc, off, 32);
    if (lane == 0) attp[i] = acc;
}

// one wave per node: softmax-max, fused weighted-V aggregate (unnormalized)
// + wsum, gated combine in place, BN per-block partial sums.
__global__ __launch_bounds__(256) void agg_kernel(
    const int* __restrict__ offs, const int* __restrict__ psrc,
    const float* __restrict__ attp, const float* __restrict__ v,
    const float* __restrict__ alpha, float* __restrict__ out,
    float* __restrict__ bnpart)
{
    __shared__ float ls[100], lq[100];
    const int tid = threadIdx.x;
    if (tid < 100) { ls[tid] = 0.f; lq[tid] = 0.f; }
    __syncthreads();
    const int lane = tid & 63;
    const int gwave = blockIdx.x * 4 + (tid >> 6);
    const int nwaves = AGG_NB * 4;
    const float a = 1.f / (1.f + __expf(-alpha[0]));
    const float b = 1.f - a;
    const int cl = lane;            // this lane owns columns 2cl, 2cl+1
    const bool act = (cl < 50);
    float sx = 0.f, sy = 0.f, qx = 0.f, qy = 0.f;

    for (int n = gwave; n < N_NODES; n += nwaves) {
        const int beg = offs[n], end = offs[n + 1];
        // segment max (lanes strided)
        float m = -INFINITY;
        for (int i = beg + lane; i < end; i += 64) m = fmaxf(m, attp[i]);
        #pragma unroll
        for (int off = 32; off > 0; off >>= 1) m = fmaxf(m, __shfl_xor(m, off, 64));
        // fused unnormalized aggregate + denom, unroll-4 for MLP
        float ax = 0.f, ay = 0.f, wsum = 0.f;
        int i = beg;
        for (; i + 4 <= end; i += 4) {
            const int s0 = psrc[i], s1 = psrc[i + 1], s2 = psrc[i + 2], s3 = psrc[i + 3];
            const float w0 = __expf(attp[i] - m),     w1 = __expf(attp[i + 1] - m);
            const float w2 = __expf(attp[i + 2] - m), w3 = __expf(attp[i + 3] - m);
            wsum += w0 + w1 + w2 + w3;
            if (act) {
                const float2 x0 = ((const float2*)(v + (size_t)s0 * 100))[cl];
                const float2 x1 = ((const float2*)(v + (size_t)s1 * 100))[cl];
                const float2 x2 = ((const float2*)(v + (size_t)s2 * 100))[cl];
                const float2 x3 = ((const float2*)(v + (size_t)s3 * 100))[cl];
                ax += w0 * x0.x + w1 * x1.x + w2 * x2.x + w3 * x3.x;
                ay += w0 * x0.y + w1 * x1.y + w2 * x2.y + w3 * x3.y;
            }
        }
        for (; i < end; ++i) {
            const int s0 = psrc[i];
            const float w0 = __expf(attp[i] - m);
            wsum += w0;
            if (act) {
                const float2 x0 = ((const float2*)(v + (size_t)s0 * 100))[cl];
                ax += w0 * x0.x;
                ay += w0 * x0.y;
            }
        }
        const float inv = (wsum > 0.f) ? 1.f / wsum : 0.f;
        if (act) {
            float2* po = (float2*)(out + (size_t)n * 100);
            float2 cur = po[cl];
            float v0 = a * cur.x + b * ax * inv;
            float v1 = a * cur.y + b * ay * inv;
            po[cl] = make_float2(v0, v1);
            sx += v0; qx += v0 * v0;
            sy += v1; qy += v1 * v1;
        }
    }
    if (act) {
        atomicAdd(&ls[2 * cl], sx);     atomicAdd(&ls[2 * cl + 1], sy);
        atomicAdd(&lq[2 * cl], qx);     atomicAdd(&lq[2 * cl + 1], qy);
    }
    __syncthreads();
    if (tid < 100) {
        bnpart[(size_t)tid * AGG_NB + blockIdx.x]         = ls[tid];
        bnpart[(size_t)(tid + 100) * AGG_NB + blockIdx.x] = lq[tid];
    }
}

// one wave per column: reduce partials -> bn scale/shift
__global__ __launch_bounds__(256) void bnfin_kernel(
    const float* __restrict__ bnpart,
    const float* __restrict__ gamma, const float* __restrict__ beta,
    float* __restrict__ bnsc, float* __restrict__ bnsh)
{
    const int c = blockIdx.x * 4 + (threadIdx.x >> 6);
    const int lane = threadIdx.x & 63;
    if (c >= 100) return;
    float s = 0.f, q = 0.f;
    for (int b2 = lane; b2 < AGG_NB; b2 += 64) {
        s += bnpart[(size_t)c * AGG_NB + b2];
        q += bnpart[(size_t)(c + 100) * AGG_NB + b2];
    }
    #pragma unroll
    for (int off = 32; off > 0; off >>= 1) {
        s += __shfl_xor(s, off, 64);
        q += __shfl_xor(q, off, 64);
    }
    if (lane == 0) {
        const float inv_n = 1.f / (float)N_NODES;
        float mean = s * inv_n;
        float var = q * inv_n - mean * mean;
        float sc = gamma[c] * rsqrtf(var + BN_EPS);
        bnsc[c] = sc;
        bnsh[c] = beta[c] - mean * sc;
    }
}

__global__ __launch_bounds__(256) void apply_kernel(
    float* __restrict__ out, const float* __restrict__ bnsc,
    const float* __restrict__ bnsh)
{
    const int total4 = N_NODES * 25;
    for (int idx = blockIdx.x * 256 + threadIdx.x; idx < total4; idx += gridDim.x * 256) {
        float4* p = ((float4*)out) + idx;
        const int c = (idx % 25) * 4;
        float4 t = *p;
        t.x = tanhf(t.x * bnsc[c]     + bnsh[c]);
        t.y = tanhf(t.y * bnsc[c + 1] + bnsh[c + 1]);
        t.z = tanhf(t.z * bnsc[c + 2] + bnsh[c + 2]);
        t.w = tanhf(t.w * bnsc[c + 3] + bnsh[c + 3]);
        *p = t;
    }
}

__global__ __launch_bounds__(256) void rout_kernel(
    const float* __restrict__ rf, const float* __restrict__ Wr,
    const float* __restrict__ br, float* __restrict__ out)
{
    int o = blockIdx.x * 256 + threadIdx.x;
    if (o >= 200 * 100) return;
    int r = o / 100, c = o % 100;
    float acc = br[c];
    #pragma unroll 10
    for (int d = 0; d < 100; ++d) acc += rf[r * 100 + d] * Wr[c * 100 + d];
    out[N_NODES * 100 + o] = acc;
}

extern "C" void kernel_launch(void* const* d_in, const int* in_sizes, int n_in,
                              void* d_out, int out_size, void* d_ws, size_t ws_size,
                              hipStream_t stream) {
    const float* X     = (const float*)d_in[0];
    const float* rfeat = (const float*)d_in[1];
    const int*   src   = (const int*)d_in[2];
    const int*   dst   = (const int*)d_in[3];
    const int*   ety   = (const int*)d_in[4];
    const float* Wsw   = (const float*)d_in[6];
    const float* Wsb   = (const float*)d_in[7];
    const float* Wkw   = (const float*)d_in[8];
    const float* Wkb   = (const float*)d_in[9];
    const float* Wqw   = (const float*)d_in[10];
    const float* Wqb   = (const float*)d_in[11];
    const float* Wvw   = (const float*)d_in[12];
    const float* Wvb   = (const float*)d_in[13];
    const float* Wrw   = (const float*)d_in[14];
    const float* Wrb   = (const float*)d_in[15];
    const float* ratt  = (const float*)d_in[16];
    const float* wcomp = (const float*)d_in[17];
    const float* alpha = (const float*)d_in[18];
    const float* gamma = (const float*)d_in[20];
    const float* beta  = (const float*)d_in[21];

    float* out = (float*)d_out;
    float* ws  = (float*)d_ws;
    if (ws_size < (size_t)WS_ELEMS * sizeof(float)) return;

    float* relw   = ws + OFS_RELW;
    float* k      = ws + OFS_K;
    float* q      = ws + OFS_Q;
    float* v      = ws + OFS_V;
    float* attp   = ws + OFS_ATTP;
    float* bnpart = ws + OFS_BNPART;
    float* bnsc   = ws + OFS_BNSC;
    float* bnsh   = ws + OFS_BNSH;
    int* cnt      = (int*)(ws + OFS_CNT);
    int* partial  = (int*)(ws + OFS_PART);
    int* bsum     = (int*)(ws + OFS_BSUM);
    int* offs     = (int*)(ws + OFS_OFFS);
    int* cursor   = (int*)(ws + OFS_CURS);
    int* perm     = (int*)(ws + OFS_PERM);
    int* psrc     = (int*)(ws + OFS_PSRC);

    hipMemsetAsync(cnt, 0, 50000 * sizeof(int), stream);
    hipMemsetAsync(cursor, 0, 50000 * sizeof(int), stream);

    relw_kernel<<<(20000 + 255) / 256, 256, 0, stream>>>(wcomp, ratt, relw);
    proj_kernel<<<(N_NODES + 63) / 64, 320, 0, stream>>>(
        X, Wkw, Wkb, Wqw, Wqb, Wvw, Wvb, Wsw, Wsb, k, q, v, out);

    hist_kernel<<<(N_EDGES + 255) / 256, 256, 0, stream>>>(dst, cnt);
    scanA_kernel<<<SCAN_NB, 1024, 0, stream>>>(cnt, partial, bsum);
    scanB_kernel<<<1, 1024, 0, stream>>>(partial, bsum, offs);
    scatter_kernel<<<(N_EDGES + 255) / 256, 256, 0, stream>>>(src, dst, offs, cursor, perm, psrc);

    attp_kernel<<<(N_EDGES + 7) / 8, 256, 0, stream>>>(
        k, q, relw, perm, src, dst, ety, attp);
    agg_kernel<<<AGG_NB, 256, 0, stream>>>(offs, psrc, attp, v, alpha, out, bnpart);
    bnfin_kernel<<<25, 256, 0, stream>>>(bnpart, gamma, beta, bnsc, bnsh);
    apply_kernel<<<2048, 256, 0, stream>>>(out, bnsc, bnsh);
    rout_kernel<<<(20000 + 255) / 256, 256, 0, stream>>>(rfeat, Wrw, Wrb, out);
}